// Round 17
// baseline (49.257 us; speedup 1.0000x reference)
//
#include <hip/hip_runtime.h>
#include <math.h>

// TopKGate: logits = x @ W^T ; softmax ; top-2 ; scatter weights + indices(float).
// x: [8192,4096] f32, W: [64,4096] f32.
// d_out (f32 flat): weights [8192*64] then indices [8192*2] as floats.
//
// MFMA path: f32 as bf16 hi/lo split, 3 passes (hh+lh+hl; ll ~2^-16 dropped).
// Round-17 = round-13/16 phase loop, but KS 8->4: each block covers a K
// QUARTER (1024 k) as two sequential 128-KB panel stages (acc carried
// across; 3 barriers total). Grid = 64 tg x 4 ks = 256 blocks = ONE round;
// partials halve to 8 MB (was 16), finalize sums 4 slices. Per-phase code
// (x ring depth 6, B ds ping-pong, SBAR fences, mfma12) byte-identical to
// the 43.8 us kernel. setprio kept (neutral, harmless).

#define TOKENS 8192
#define DIM    4096
#define NEXP   64

#define KS     4                             // k-split across blocks
#define KSEG   (DIM / KS)                    // 1024 k per block
#define PNK    512                           // k per panel stage
#define NCH    (PNK / 32)                    // 16 chunks per stage

#define SBAR() __builtin_amdgcn_sched_barrier(0)

typedef __attribute__((ext_vector_type(8))) short  short8;
typedef __attribute__((ext_vector_type(4))) float  f32x4;
typedef __attribute__((ext_vector_type(8))) float  f32x8;

__device__ __forceinline__ void bf16split(float v, short& hi, short& lo) {
    unsigned u = __float_as_uint(v);
    hi = (short)(u >> 16);
    float r = v - __uint_as_float(u & 0xffff0000u);
    lo = (short)(__float_as_uint(r) >> 16);
}

// ---- main: 128 tokens/block (8 waves x 16), 2 sequential B panel stages ----
__global__ __launch_bounds__(512, 2)
void tg_mfma(const float* __restrict__ x, const float* __restrict__ W,
             float* __restrict__ part) {
    // B panel: [hi/lo][chunk][nt][lane] short8 = 128 KB
    __shared__ short8 Bls[2][NCH][4][64];

    const int tid  = threadIdx.x;
    const int lane = tid & 63;
    const int wave = tid >> 6;                   // token sub-group 0..7
    const int tg   = blockIdx.x >> 2;            // token group 0..63
    const int ks   = blockIdx.x & 3;             // k quarter 0..3
    const int t0   = tg * 128 + wave * 16;
    const int row  = lane & 15;                  // A row (token) / D col tag
    const int grp  = lane >> 4;

    f32x4 acc[4];
#pragma unroll
    for (int nt = 0; nt < 4; ++nt) acc[nt] = (f32x4){0.f, 0.f, 0.f, 0.f};

    short8 bA[8], bB[8];
    auto dsB = [&](short8 (&b)[8], int c) {      // 8 x ds_read_b128, conflict-free
#pragma unroll
        for (int nt = 0; nt < 4; ++nt) {
            b[nt]     = Bls[0][c][nt][lane];
            b[4 + nt] = Bls[1][c][nt][lane];
        }
    };
    auto cvt = [&](const f32x8& xv, short8& ah, short8& al) {
#pragma unroll
        for (int j = 0; j < 8; ++j) {
            short hh, ll;
            bf16split(xv[j], hh, ll);
            ah[j] = hh; al[j] = ll;
        }
    };
    auto mfma12 = [&](const short8& ah, const short8& al, const short8 (&b)[8]) {
        // 3-pass split: hh + lh + hl (ll ~ 2^-16 relative, dropped)
        __builtin_amdgcn_s_setprio(1);
#pragma unroll
        for (int nt = 0; nt < 4; ++nt)
            acc[nt] = __builtin_amdgcn_mfma_f32_16x16x32_bf16(ah, b[nt], acc[nt], 0, 0, 0);
#pragma unroll
        for (int nt = 0; nt < 4; ++nt)
            acc[nt] = __builtin_amdgcn_mfma_f32_16x16x32_bf16(al, b[nt], acc[nt], 0, 0, 0);
#pragma unroll
        for (int nt = 0; nt < 4; ++nt)
            acc[nt] = __builtin_amdgcn_mfma_f32_16x16x32_bf16(ah, b[4 + nt], acc[nt], 0, 0, 0);
        __builtin_amdgcn_s_setprio(0);
    };

#pragma unroll 1
    for (int half = 0; half < 2; ++half) {
        const int k0 = ks * KSEG + half * PNK;   // panel k-base

        // ---- B prep into LDS (validated mapping); overwrite needs a guard
        if (half) __syncthreads();               // all waves done reading stage 0
#pragma unroll
        for (int s8 = 0; s8 < 8; ++s8) {
            const int s   = s8 * 512 + tid;
            const int c   = s >> 8;
            const int rem = s & 255;
            const int nt  = rem >> 6;
            const int ln  = rem & 63;
            const int e   = nt * 16 + (ln & 15);
            const int kb  = k0 + c * 32 + (ln >> 4) * 8;
            const f32x8 wv = *reinterpret_cast<const f32x8*>(W + (size_t)e * DIM + kb);
            short8 h, l;
#pragma unroll
            for (int j = 0; j < 8; ++j) {
                short hh, ll;
                bf16split(wv[j], hh, ll);
                h[j] = hh; l[j] = ll;
            }
            Bls[0][c][nt][ln] = h;
            Bls[1][c][nt][ln] = l;
        }
        __syncthreads();

        const float* xp = x + (size_t)(t0 + row) * DIM + k0 + grp * 8;
        auto ldx = [&](int c) {
            return *reinterpret_cast<const f32x8*>(xp + c * 32);
        };

        // prologue: B(0) from LDS, x ring depth 6 in flight
        f32x8 x0 = ldx(0), x1 = ldx(1), x2 = ldx(2),
              x3 = ldx(3), x4 = ldx(4), x5 = ldx(5);
        dsB(bA, 0);
        SBAR();

        short8 ah, al;
#define PH(c, XV, BC, BN)                                            \
    {                                                                \
        cvt(XV, ah, al);          /* convert frees XV's slot */      \
        SBAR();                                                      \
        if ((c) + 1 < NCH) dsB(BN, (c) + 1);                         \
        if ((c) + 6 < NCH) XV = ldx((c) + 6);                        \
        SBAR();                                                      \
        mfma12(ah, al, BC);                                          \
        SBAR();                                                      \
    }

        PH(0,  x0, bA, bB)
        PH(1,  x1, bB, bA)
        PH(2,  x2, bA, bB)
        PH(3,  x3, bB, bA)
        PH(4,  x4, bA, bB)
        PH(5,  x5, bB, bA)
        PH(6,  x0, bA, bB)
        PH(7,  x1, bB, bA)
        PH(8,  x2, bA, bB)
        PH(9,  x3, bB, bA)
        PH(10, x4, bA, bB)
        PH(11, x5, bB, bA)
        PH(12, x0, bA, bB)
        PH(13, x1, bB, bA)
        PH(14, x2, bA, bB)
        PH(15, x3, bB, bA)
#undef PH
    }

    // ---- direct partial write: wave owns its 16 tokens, no reduction ----
    // D layout (m89-verified): col = lane&15, row = grp*4 + reg
    float* pp = part + ((size_t)ks * TOKENS + t0) * NEXP;
#pragma unroll
    for (int nt = 0; nt < 4; ++nt)
#pragma unroll
        for (int r = 0; r < 4; ++r)
            pp[(grp * 4 + r) * NEXP + nt * 16 + row] = acc[nt][r];
}

// ---- finalize: sum 4 k-split partials, wave-per-token softmax + top-2 ----
__global__ __launch_bounds__(256)
void tg_final(const float* __restrict__ part,
              float* __restrict__ out_w, float* __restrict__ out_i) {
    const int lane = threadIdx.x & 63;
    const int wv   = threadIdx.x >> 6;
    const int t    = blockIdx.x * 4 + wv;        // one token per wave

    float s = 0.0f;
#pragma unroll
    for (int k = 0; k < KS; ++k)                 // coalesced 256-B reads
        s += part[((size_t)k * TOKENS + t) * NEXP + lane];

    // softmax over 64 lanes (butterfly: all lanes converge bit-identically)
    float m = s;
#pragma unroll
    for (int o = 32; o > 0; o >>= 1) m = fmaxf(m, __shfl_xor(m, o));
    float p = expf(s - m);
    float sum = p;
#pragma unroll
    for (int o = 32; o > 0; o >>= 1) sum += __shfl_xor(sum, o);
    const float prob = p / sum;

    // top-1: max value, tie -> lower index (jax top_k order)
    float v1 = prob; int i1 = lane;
#pragma unroll
    for (int o = 32; o > 0; o >>= 1) {
        float ov = __shfl_xor(v1, o); int oi = __shfl_xor(i1, o);
        if (ov > v1 || (ov == v1 && oi < i1)) { v1 = ov; i1 = oi; }
    }
    // top-2: mask winner (probs >= 0 > -1)
    float v2 = (lane == i1) ? -1.0f : prob; int i2 = lane;
#pragma unroll
    for (int o = 32; o > 0; o >>= 1) {
        float ov = __shfl_xor(v2, o); int oi = __shfl_xor(i2, o);
        if (ov > v2 || (ov == v2 && oi < i2)) { v2 = ov; i2 = oi; }
    }

    out_w[(size_t)t * NEXP + lane] = (lane == i1) ? v1 : (lane == i2) ? v2 : 0.0f;
    if (lane == 0) {
        out_i[(size_t)t * 2 + 0] = (float)i1;
        out_i[(size_t)t * 2 + 1] = (float)i2;
    }
}

extern "C" void kernel_launch(void* const* d_in, const int* in_sizes, int n_in,
                              void* d_out, int out_size, void* d_ws, size_t ws_size,
                              hipStream_t stream) {
    const float* x = (const float*)d_in[0];
    const float* W = (const float*)d_in[1];
    float* out_w = (float*)d_out;
    float* out_i = out_w + (size_t)TOKENS * NEXP;

    float* part = (float*)d_ws;   // KS * 8192 * 64 f32 = 8 MB

    tg_mfma <<<dim3((TOKENS / 128) * KS), dim3(512), 0, stream>>>(x, W, part);
    tg_final<<<dim3(TOKENS / 4), dim3(256), 0, stream>>>(part, out_w, out_i);
}

// Round 18
// 43.448 us; speedup vs baseline: 1.1337x; 1.1337x over previous
//
#include <hip/hip_runtime.h>
#include <math.h>

// TopKGate: logits = x @ W^T ; softmax ; top-2 ; scatter weights + indices(float).
// x: [8192,4096] f32, W: [64,4096] f32.
// d_out (f32 flat): weights [8192*64] then indices [8192*2] as floats.
//
// MFMA path: f32 as bf16 hi/lo split, 3 passes (hh+lh+hl; ll ~2^-16 dropped).
// Round-18 = round-16 (43.8us best: KS=8, in-kernel B prep, 128KB panel,
// x-only vmem ring depth 6, setprio) with PAIRED PHASES: 8 phases x 2 chunks
// (was 16 x 1). R17's L3-resident replays proved time is independent of the
// x source (FETCH 67->8.4 MB, same dur) -> bound by per-phase fixed cost,
// not bandwidth. Halving phase boundaries attacks exactly that. All totals
// (loads, MFMAs, LDS traffic, ring depth, ping-pong distance) unchanged.

#define TOKENS 8192
#define DIM    4096
#define NEXP   64

#define KS     8                             // k-split across blocks
#define KSEG   (DIM / KS)                    // 512 k per block
#define NCH    (KSEG / 32)                   // 16 chunks per block

#define SBAR() __builtin_amdgcn_sched_barrier(0)

typedef __attribute__((ext_vector_type(8))) short  short8;
typedef __attribute__((ext_vector_type(4))) float  f32x4;
typedef __attribute__((ext_vector_type(8))) float  f32x8;

__device__ __forceinline__ void bf16split(float v, short& hi, short& lo) {
    unsigned u = __float_as_uint(v);
    hi = (short)(u >> 16);
    float r = v - __uint_as_float(u & 0xffff0000u);
    lo = (short)(__float_as_uint(r) >> 16);
}

// ---- main: 128 tokens/block (8 waves x 16), B panel built in-kernel ----
__global__ __launch_bounds__(512, 2)
void tg_mfma(const float* __restrict__ x, const float* __restrict__ W,
             float* __restrict__ part) {
    // B panel: [hi/lo][chunk][nt][lane] short8 = 128 KB
    __shared__ short8 Bls[2][NCH][4][64];

    const int tid  = threadIdx.x;
    const int lane = tid & 63;
    const int wave = tid >> 6;                   // token sub-group 0..7
    const int tg   = blockIdx.x >> 3;            // token group 0..63
    const int ks   = blockIdx.x & 7;             // k split 0..7
    const int t0   = tg * 128 + wave * 16;
    const int row  = lane & 15;                  // A row (token) / D col tag
    const int grp  = lane >> 4;

    // ---- in-kernel B prep (validated): slot s -> c,nt,ln ----
    // e = nt*16+(ln&15), k = ks*KSEG + c*32 + (ln>>4)*8
#pragma unroll
    for (int s8 = 0; s8 < 8; ++s8) {
        const int s   = s8 * 512 + tid;
        const int c   = s >> 8;
        const int rem = s & 255;
        const int nt  = rem >> 6;
        const int ln  = rem & 63;
        const int e   = nt * 16 + (ln & 15);
        const int kb  = ks * KSEG + c * 32 + (ln >> 4) * 8;
        const f32x8 wv = *reinterpret_cast<const f32x8*>(W + (size_t)e * DIM + kb);
        short8 h, l;
#pragma unroll
        for (int j = 0; j < 8; ++j) {
            short hh, ll;
            bf16split(wv[j], hh, ll);
            h[j] = hh; l[j] = ll;
        }
        Bls[0][c][nt][ln] = h;
        Bls[1][c][nt][ln] = l;
    }
    __syncthreads();   // the only barrier in the kernel

    const float* xp = x + (size_t)(t0 + row) * DIM + ks * KSEG + grp * 8;

    f32x4 acc[4];
#pragma unroll
    for (int nt = 0; nt < 4; ++nt) acc[nt] = (f32x4){0.f, 0.f, 0.f, 0.f};

    short8 bA[8], bB[8];
    auto dsB = [&](short8 (&b)[8], int c) {      // 8 x ds_read_b128, conflict-free
#pragma unroll
        for (int nt = 0; nt < 4; ++nt) {
            b[nt]     = Bls[0][c][nt][lane];
            b[4 + nt] = Bls[1][c][nt][lane];
        }
    };
    auto ldx = [&](int c) {
        return *reinterpret_cast<const f32x8*>(xp + c * 32);
    };
    auto cvt = [&](const f32x8& xv, short8& ah, short8& al) {
#pragma unroll
        for (int j = 0; j < 8; ++j) {
            short hh, ll;
            bf16split(xv[j], hh, ll);
            ah[j] = hh; al[j] = ll;
        }
    };
    auto mfma12 = [&](const short8& ah, const short8& al, const short8 (&b)[8]) {
        // 3-pass split: hh + lh + hl (ll ~ 2^-16 relative, dropped)
        __builtin_amdgcn_s_setprio(1);
#pragma unroll
        for (int nt = 0; nt < 4; ++nt)
            acc[nt] = __builtin_amdgcn_mfma_f32_16x16x32_bf16(ah, b[nt], acc[nt], 0, 0, 0);
#pragma unroll
        for (int nt = 0; nt < 4; ++nt)
            acc[nt] = __builtin_amdgcn_mfma_f32_16x16x32_bf16(al, b[nt], acc[nt], 0, 0, 0);
#pragma unroll
        for (int nt = 0; nt < 4; ++nt)
            acc[nt] = __builtin_amdgcn_mfma_f32_16x16x32_bf16(ah, b[4 + nt], acc[nt], 0, 0, 0);
        __builtin_amdgcn_s_setprio(0);
    };

    // prologue: B(0),B(1) from LDS, x ring depth 6 in flight
    f32x8 x0 = ldx(0), x1 = ldx(1), x2 = ldx(2),
          x3 = ldx(3), x4 = ldx(4), x5 = ldx(5);
    dsB(bA, 0);
    dsB(bB, 1);
    SBAR();

    short8 ah, al;
    // paired phase p: chunks 2p (bA) and 2p+1 (bB); one fence cluster per pair
#define PPH(p, XA, XB)                                               \
    {                                                                \
        cvt(XA, ah, al);                                             \
        mfma12(ah, al, bA);                                          \
        cvt(XB, ah, al);                                             \
        mfma12(ah, al, bB);                                          \
        SBAR();                                                      \
        if (2*(p) + 2 < NCH) dsB(bA, 2*(p) + 2);                     \
        if (2*(p) + 3 < NCH) dsB(bB, 2*(p) + 3);                     \
        if (2*(p) + 6 < NCH) XA = ldx(2*(p) + 6);                    \
        if (2*(p) + 7 < NCH) XB = ldx(2*(p) + 7);                    \
        SBAR();                                                      \
    }

    PPH(0, x0, x1)
    PPH(1, x2, x3)
    PPH(2, x4, x5)
    PPH(3, x0, x1)
    PPH(4, x2, x3)
    PPH(5, x4, x5)
    PPH(6, x0, x1)
    PPH(7, x2, x3)
#undef PPH

    // ---- direct partial write: wave owns its 16 tokens, no reduction ----
    // D layout (m89-verified): col = lane&15, row = grp*4 + reg
    float* pp = part + ((size_t)ks * TOKENS + t0) * NEXP;
#pragma unroll
    for (int nt = 0; nt < 4; ++nt)
#pragma unroll
        for (int r = 0; r < 4; ++r)
            pp[(grp * 4 + r) * NEXP + nt * 16 + row] = acc[nt][r];
}

// ---- finalize: sum 8 k-split partials, wave-per-token softmax + top-2 ----
__global__ __launch_bounds__(256)
void tg_final(const float* __restrict__ part,
              float* __restrict__ out_w, float* __restrict__ out_i) {
    const int lane = threadIdx.x & 63;
    const int wv   = threadIdx.x >> 6;
    const int t    = blockIdx.x * 4 + wv;        // one token per wave

    float s = 0.0f;
#pragma unroll
    for (int k = 0; k < KS; ++k)                 // coalesced 256-B reads
        s += part[((size_t)k * TOKENS + t) * NEXP + lane];

    // softmax over 64 lanes (butterfly: all lanes converge bit-identically)
    float m = s;
#pragma unroll
    for (int o = 32; o > 0; o >>= 1) m = fmaxf(m, __shfl_xor(m, o));
    float p = expf(s - m);
    float sum = p;
#pragma unroll
    for (int o = 32; o > 0; o >>= 1) sum += __shfl_xor(sum, o);
    const float prob = p / sum;

    // top-1: max value, tie -> lower index (jax top_k order)
    float v1 = prob; int i1 = lane;
#pragma unroll
    for (int o = 32; o > 0; o >>= 1) {
        float ov = __shfl_xor(v1, o); int oi = __shfl_xor(i1, o);
        if (ov > v1 || (ov == v1 && oi < i1)) { v1 = ov; i1 = oi; }
    }
    // top-2: mask winner (probs >= 0 > -1)
    float v2 = (lane == i1) ? -1.0f : prob; int i2 = lane;
#pragma unroll
    for (int o = 32; o > 0; o >>= 1) {
        float ov = __shfl_xor(v2, o); int oi = __shfl_xor(i2, o);
        if (ov > v2 || (ov == v2 && oi < i2)) { v2 = ov; i2 = oi; }
    }

    out_w[(size_t)t * NEXP + lane] = (lane == i1) ? v1 : (lane == i2) ? v2 : 0.0f;
    if (lane == 0) {
        out_i[(size_t)t * 2 + 0] = (float)i1;
        out_i[(size_t)t * 2 + 1] = (float)i2;
    }
}

extern "C" void kernel_launch(void* const* d_in, const int* in_sizes, int n_in,
                              void* d_out, int out_size, void* d_ws, size_t ws_size,
                              hipStream_t stream) {
    const float* x = (const float*)d_in[0];
    const float* W = (const float*)d_in[1];
    float* out_w = (float*)d_out;
    float* out_i = out_w + (size_t)TOKENS * NEXP;

    float* part = (float*)d_ws;   // KS * 8192 * 64 f32 = 16 MB

    tg_mfma <<<dim3((TOKENS / 128) * KS), dim3(512), 0, stream>>>(x, W, part);
    tg_final<<<dim3(TOKENS / 4), dim3(256), 0, stream>>>(part, out_w, out_i);
}

// Round 19
// 41.201 us; speedup vs baseline: 1.1955x; 1.0545x over previous
//
#include <hip/hip_runtime.h>
#include <math.h>

// TopKGate: logits = x @ W^T ; softmax ; top-2 ; scatter weights + indices(float).
// x: [8192,4096] f32, W: [64,4096] f32.
// d_out (f32 flat): weights [8192*64] then indices [8192*2] as floats.
//
// MFMA path: f32 as bf16 hi/lo split, 3 passes (hh+lh+hl; ll ~2^-16 dropped).
// Round-19: occupancy 8 -> 16 waves/CU. Panel halved to 64 KB (K=256/stage,
// 2 stages/block, KS=8 unchanged) -> 2 co-resident 512-thr blocks per CU;
// stage-prep of one block hides under compute of the other. Register diet
// to fit the 128-VGPR cap of launch_bounds(512,4): single B buffer (32),
// x ring depth 4 (32), acc 16, ah/al 8 -> ~110 total. x ring refills run
// uninterrupted across the stage boundary (prefetch next stage's chunks).

#define TOKENS 8192
#define DIM    4096
#define NEXP   64

#define KS     8                             // k-split across blocks
#define KSEG   (DIM / KS)                    // 512 k per block
#define NCHB   (KSEG / 32)                   // 16 chunks per block
#define PNK    256                           // k per panel stage
#define NCHP   (PNK / 32)                    // 8 chunks per stage

#define SBAR() __builtin_amdgcn_sched_barrier(0)

typedef __attribute__((ext_vector_type(8))) short  short8;
typedef __attribute__((ext_vector_type(4))) float  f32x4;
typedef __attribute__((ext_vector_type(8))) float  f32x8;

__device__ __forceinline__ void bf16split(float v, short& hi, short& lo) {
    unsigned u = __float_as_uint(v);
    hi = (short)(u >> 16);
    float r = v - __uint_as_float(u & 0xffff0000u);
    lo = (short)(__float_as_uint(r) >> 16);
}

// ---- main: 128 tokens/block (8 waves x 16), 2-stage 64 KB B panel ----
__global__ __launch_bounds__(512, 4)
void tg_mfma(const float* __restrict__ x, const float* __restrict__ W,
             float* __restrict__ part) {
    // B panel: [hi/lo][chunk][nt][lane] short8 = 64 KB
    __shared__ short8 Bls[2][NCHP][4][64];

    const int tid  = threadIdx.x;
    const int lane = tid & 63;
    const int wave = tid >> 6;                   // token sub-group 0..7
    const int tg   = blockIdx.x >> 3;            // token group 0..63
    const int ks   = blockIdx.x & 7;             // k split 0..7
    const int t0   = tg * 128 + wave * 16;
    const int row  = lane & 15;                  // A row (token) / D col tag
    const int grp  = lane >> 4;

    const float* xp = x + (size_t)(t0 + row) * DIM + ks * KSEG + grp * 8;
    auto ldx = [&](int c) {                      // c = global chunk 0..15
        return *reinterpret_cast<const f32x8*>(xp + c * 32);
    };

    // issue the x ring FIRST so it's deep in flight during stage-0 prep
    f32x8 x0 = ldx(0), x1 = ldx(1), x2 = ldx(2), x3 = ldx(3);

    // ---- B prep for one stage (validated mapping), 4 slots/thread ----
    auto prep = [&](int stage) {
        const int k0 = ks * KSEG + stage * PNK;
#pragma unroll
        for (int s4 = 0; s4 < 4; ++s4) {
            const int s   = s4 * 512 + tid;      // 0..2047
            const int c   = s >> 8;              // 0..7
            const int rem = s & 255;
            const int nt  = rem >> 6;
            const int ln  = rem & 63;
            const int e   = nt * 16 + (ln & 15);
            const int kb  = k0 + c * 32 + (ln >> 4) * 8;
            const f32x8 wv = *reinterpret_cast<const f32x8*>(W + (size_t)e * DIM + kb);
            short8 h, l;
#pragma unroll
            for (int j = 0; j < 8; ++j) {
                short hh, ll;
                bf16split(wv[j], hh, ll);
                h[j] = hh; l[j] = ll;
            }
            Bls[0][c][nt][ln] = h;
            Bls[1][c][nt][ln] = l;
        }
    };

    f32x4 acc[4];
#pragma unroll
    for (int nt = 0; nt < 4; ++nt) acc[nt] = (f32x4){0.f, 0.f, 0.f, 0.f};

    short8 b[8];
    auto dsB = [&](int c) {                      // 8 x ds_read_b128, conflict-free
#pragma unroll
        for (int nt = 0; nt < 4; ++nt) {
            b[nt]     = Bls[0][c][nt][lane];
            b[4 + nt] = Bls[1][c][nt][lane];
        }
    };
    auto cvt = [&](const f32x8& xv, short8& ah, short8& al) {
#pragma unroll
        for (int j = 0; j < 8; ++j) {
            short hh, ll;
            bf16split(xv[j], hh, ll);
            ah[j] = hh; al[j] = ll;
        }
    };
    auto mfma12 = [&](const short8& ah, const short8& al) {
        // 3-pass split: hh + lh + hl (ll ~ 2^-16 relative, dropped)
        __builtin_amdgcn_s_setprio(1);
#pragma unroll
        for (int nt = 0; nt < 4; ++nt)
            acc[nt] = __builtin_amdgcn_mfma_f32_16x16x32_bf16(ah, b[nt], acc[nt], 0, 0, 0);
#pragma unroll
        for (int nt = 0; nt < 4; ++nt)
            acc[nt] = __builtin_amdgcn_mfma_f32_16x16x32_bf16(al, b[nt], acc[nt], 0, 0, 0);
#pragma unroll
        for (int nt = 0; nt < 4; ++nt)
            acc[nt] = __builtin_amdgcn_mfma_f32_16x16x32_bf16(ah, b[4 + nt], acc[nt], 0, 0, 0);
        __builtin_amdgcn_s_setprio(0);
    };

    prep(0);
    __syncthreads();

    short8 ah, al;
    // phase: dsB issue -> cvt (covers LDS latency) + x refill -> mfma
#define PH(cg, cl, XV)                                               \
    {                                                                \
        dsB(cl);                                                     \
        SBAR();                                                      \
        cvt(XV, ah, al);                                             \
        if ((cg) + 4 < NCHB) XV = ldx((cg) + 4);                     \
        SBAR();                                                      \
        mfma12(ah, al);                                              \
        SBAR();                                                      \
    }

    // stage 0: global chunks 0..7
    PH(0, 0, x0)  PH(1, 1, x1)  PH(2, 2, x2)  PH(3, 3, x3)
    PH(4, 4, x0)  PH(5, 5, x1)  PH(6, 6, x2)  PH(7, 7, x3)

    __syncthreads();          // all waves done reading stage-0 panel
    prep(1);
    __syncthreads();

    // stage 1: global chunks 8..15 (x ring already holds 8..11)
    PH(8,  0, x0)  PH(9,  1, x1)  PH(10, 2, x2)  PH(11, 3, x3)
    PH(12, 4, x0)  PH(13, 5, x1)  PH(14, 6, x2)  PH(15, 7, x3)
#undef PH

    // ---- direct partial write: wave owns its 16 tokens, no reduction ----
    // D layout (m89-verified): col = lane&15, row = grp*4 + reg
    float* pp = part + ((size_t)ks * TOKENS + t0) * NEXP;
#pragma unroll
    for (int nt = 0; nt < 4; ++nt)
#pragma unroll
        for (int r = 0; r < 4; ++r)
            pp[(grp * 4 + r) * NEXP + nt * 16 + row] = acc[nt][r];
}

// ---- finalize: sum 8 k-split partials, wave-per-token softmax + top-2 ----
__global__ __launch_bounds__(256)
void tg_final(const float* __restrict__ part,
              float* __restrict__ out_w, float* __restrict__ out_i) {
    const int lane = threadIdx.x & 63;
    const int wv   = threadIdx.x >> 6;
    const int t    = blockIdx.x * 4 + wv;        // one token per wave

    float s = 0.0f;
#pragma unroll
    for (int k = 0; k < KS; ++k)                 // coalesced 256-B reads
        s += part[((size_t)k * TOKENS + t) * NEXP + lane];

    // softmax over 64 lanes (butterfly: all lanes converge bit-identically)
    float m = s;
#pragma unroll
    for (int o = 32; o > 0; o >>= 1) m = fmaxf(m, __shfl_xor(m, o));
    float p = expf(s - m);
    float sum = p;
#pragma unroll
    for (int o = 32; o > 0; o >>= 1) sum += __shfl_xor(sum, o);
    const float prob = p / sum;

    // top-1: max value, tie -> lower index (jax top_k order)
    float v1 = prob; int i1 = lane;
#pragma unroll
    for (int o = 32; o > 0; o >>= 1) {
        float ov = __shfl_xor(v1, o); int oi = __shfl_xor(i1, o);
        if (ov > v1 || (ov == v1 && oi < i1)) { v1 = ov; i1 = oi; }
    }
    // top-2: mask winner (probs >= 0 > -1)
    float v2 = (lane == i1) ? -1.0f : prob; int i2 = lane;
#pragma unroll
    for (int o = 32; o > 0; o >>= 1) {
        float ov = __shfl_xor(v2, o); int oi = __shfl_xor(i2, o);
        if (ov > v2 || (ov == v2 && oi < i2)) { v2 = ov; i2 = oi; }
    }

    out_w[(size_t)t * NEXP + lane] = (lane == i1) ? v1 : (lane == i2) ? v2 : 0.0f;
    if (lane == 0) {
        out_i[(size_t)t * 2 + 0] = (float)i1;
        out_i[(size_t)t * 2 + 1] = (float)i2;
    }
}

extern "C" void kernel_launch(void* const* d_in, const int* in_sizes, int n_in,
                              void* d_out, int out_size, void* d_ws, size_t ws_size,
                              hipStream_t stream) {
    const float* x = (const float*)d_in[0];
    const float* W = (const float*)d_in[1];
    float* out_w = (float*)d_out;
    float* out_i = out_w + (size_t)TOKENS * NEXP;

    float* part = (float*)d_ws;   // KS * 8192 * 64 f32 = 16 MB

    tg_mfma <<<dim3((TOKENS / 128) * KS), dim3(512), 0, stream>>>(x, W, part);
    tg_final<<<dim3(TOKENS / 4), dim3(256), 0, stream>>>(part, out_w, out_i);
}